// Round 7
// baseline (770.054 us; speedup 1.0000x reference)
//
#include <hip/hip_runtime.h>
#include <hip/hip_fp16.h>

// Trilinear grid interpolation — fp16 repack + uv-binning for L1 residency.
//   velocity: [B, 3, G, G, G] f32, points: [B, N, 3] f32, bb: [3,2] f32
//   out: [B, N, 3] f32
//
// Model from R1-R5: gather time ~= 5 cyc/L1-miss-line + ~1 cyc/L1-hit request
// (+ broadcast-scan overhead). R5 (packed cells, slab->XCD pinned) still
// misses every touch (random over 2MB slab >> 32KB L1).
// R6: bin points by (iu1/4, iv1/4). One bin's packed working set =
// 5x5x128x8B ~ 25.6KB < L1 -> only first-touch misses (~2/point vs 4.5),
// and the 8x-redundant broadcast scan is gone. Pipeline:
//   repack -> count -> scan -> scatter(payload u,v,w,idx) -> binned gather.
// Gather block index keeps blockIdx%8 == slab (iu/16) for XCD L2 pinning.

constexpr int G = 128;
constexpr long long G3 = (long long)G * G * G;
constexpr int NSLAB = 8;            // == #XCDs
constexpr int NBU = 32, NBV = 32;   // 4x4-cell uv bins
// bin linear id = (b*NBU + iu4)*NBV + iv4

// ---------------- repack: [B,3,G3] f32 -> [B,G3] 8B cells (3xfp16+pad) ------
__global__ __launch_bounds__(256) void repack_kernel(
    const float* __restrict__ vel, uint2* __restrict__ grid8)
{
    long long t = (long long)blockIdx.x * 256 + threadIdx.x;  // 4-cell unit
    long long cell4 = t * 4;
    int bw = (int)(cell4 / G3);
    int ci = (int)(cell4 % G3);
    long long vbase = ((long long)bw * 3) * G3;

    float4 v0 = *reinterpret_cast<const float4*>(vel + vbase + ci);
    float4 v1 = *reinterpret_cast<const float4*>(vel + vbase + G3 + ci);
    float4 v2 = *reinterpret_cast<const float4*>(vel + vbase + 2 * G3 + ci);

    auto pk = [](float a, float b) -> unsigned int {
        unsigned int ua = __half_as_ushort(__float2half(a));
        unsigned int ub = __half_as_ushort(__float2half(b));
        return ua | (ub << 16);
    };
    auto pq = [](float c) -> unsigned int {
        return (unsigned int)__half_as_ushort(__float2half(c));
    };

    uint4 d0, d1;
    d0.x = pk(v0.x, v1.x); d0.y = pq(v2.x);
    d0.z = pk(v0.y, v1.y); d0.w = pq(v2.y);
    d1.x = pk(v0.z, v1.z); d1.y = pq(v2.z);
    d1.z = pk(v0.w, v1.w); d1.w = pq(v2.w);

    uint4* dst = reinterpret_cast<uint4*>(grid8 + (long long)bw * G3 + ci);
    dst[0] = d0;
    dst[1] = d1;
}

// ---------------- pass 1a: per-bin counts ----------------
__global__ __launch_bounds__(256) void count_kernel(
    const float* __restrict__ pts, const float* __restrict__ bb,
    int* __restrict__ cnt, int N, int total)
{
    int t = blockIdx.x * 256 + threadIdx.x;
    if (t >= total) return;
    int b = t / N;
    const float Gm1 = (float)(G - 1);
    float bx0 = bb[0], bx1 = bb[1];
    float by0 = bb[2], by1 = bb[3];
    float px = pts[(long long)t * 3];
    float py = pts[(long long)t * 3 + 1];
    float u = (px - bx0) / (bx1 - bx0) * Gm1;
    float v = (py - by0) / (by1 - by0) * Gm1;
    int iu1 = (int)fminf(fmaxf(floorf(u), 0.f), Gm1);
    int iv1 = (int)fminf(fmaxf(floorf(v), 0.f), Gm1);
    int bin = (b * NBU + (iu1 >> 2)) * NBV + (iv1 >> 2);
    atomicAdd(&cnt[bin], 1);
}

// ---------------- pass 1b: exclusive scan over nbins (one block) ------------
__global__ __launch_bounds__(1024) void scan_kernel(
    const int* __restrict__ cnt, int* __restrict__ base,
    int* __restrict__ cursor, int nbins)
{
    __shared__ int sh[1024];
    int t = threadIdx.x;
    int per = nbins / 1024;            // nbins = B*1024 -> divisible
    int local[64];                     // per <= 64 supported (B <= 64)
    int s = 0;
    for (int j = 0; j < per; ++j) { local[j] = cnt[t * per + j]; s += local[j]; }
    sh[t] = s;
    __syncthreads();
    for (int off = 1; off < 1024; off <<= 1) {
        int v = (t >= off) ? sh[t - off] : 0;
        __syncthreads();
        sh[t] += v;
        __syncthreads();
    }
    int run = sh[t] - s;               // exclusive prefix for this thread
    for (int j = 0; j < per; ++j) {
        base[t * per + j] = run;
        cursor[t * per + j] = run;
        run += local[j];
    }
    if (t == 1023) base[nbins] = sh[1023];
}

// ---------------- pass 1c: scatter payload {u,v,w,idx} ----------------
__global__ __launch_bounds__(256) void scatter_kernel(
    const float* __restrict__ pts, const float* __restrict__ bb,
    int* __restrict__ cursor, float4* __restrict__ payload,
    int N, int total)
{
    int t = blockIdx.x * 256 + threadIdx.x;
    if (t >= total) return;
    int b = t / N;
    const float Gm1 = (float)(G - 1);
    float bx0 = bb[0], bx1 = bb[1];
    float by0 = bb[2], by1 = bb[3];
    float bz0 = bb[4], bz1 = bb[5];
    float px = pts[(long long)t * 3];
    float py = pts[(long long)t * 3 + 1];
    float pz = pts[(long long)t * 3 + 2];
    float u = (px - bx0) / (bx1 - bx0) * Gm1;
    float v = (py - by0) / (by1 - by0) * Gm1;
    float w = (pz - bz0) / (bz1 - bz0) * Gm1;
    int iu1 = (int)fminf(fmaxf(floorf(u), 0.f), Gm1);
    int iv1 = (int)fminf(fmaxf(floorf(v), 0.f), Gm1);
    int bin = (b * NBU + (iu1 >> 2)) * NBV + (iv1 >> 2);
    int pos = atomicAdd(&cursor[bin], 1);
    payload[pos] = make_float4(u, v, w, __int_as_float(t));
}

// ---------------- pass 2: binned gather (one 128-thread block per bin) ------
__global__ __launch_bounds__(128) void trilerp_binned_kernel(
    const uint2* __restrict__ grid8,     // [B,G3]
    const int* __restrict__ base,        // [nbins+1]
    const float4* __restrict__ payload,  // [B*N]
    float* __restrict__ out)             // [B,N,3]
{
    // blockIdx.x = slab + 8*(b*128 + (iu4&3)*32 + iv4)  -> blockIdx%8 == XCD slab
    int x = blockIdx.x;
    int slab = x & (NSLAB - 1);
    int rest = x >> 3;
    int b    = rest >> 7;
    int r2   = rest & 127;
    int iu4  = (slab << 2) | (r2 >> 5);
    int iv4  = r2 & 31;
    int bin  = (b * NBU + iu4) * NBV + iv4;

    int s = base[bin], e = base[bin + 1];
    const uint2* gb8 = grid8 + (long long)b * G3;
    const float Gm1 = (float)(G - 1);

    for (int i = s + (int)threadIdx.x; i < e; i += 128) {
        float4 pl = payload[i];
        float u = pl.x, v = pl.y, w = pl.z;
        int t = __float_as_int(pl.w);

        float fu = fminf(fmaxf(floorf(u), 0.f), Gm1);
        float fv = fminf(fmaxf(floorf(v), 0.f), Gm1);
        float fw = fminf(fmaxf(floorf(w), 0.f), Gm1);

        float du = u - fu, dv = v - fv, dw = w - fw;   // frac
        float gu = fu + 1.0f - u;                      // gfrac
        float gv = fv + 1.0f - v;
        float gw = fw + 1.0f - w;

        int iu1 = (int)fu, iv1 = (int)fv, iw1 = (int)fw;
        int iu2 = min(iu1 + 1, G - 1);
        int iv2 = min(iv1 + 1, G - 1);

        int iwb = min(iw1, G - 2);
        bool lo = (iw1 <= G - 2);

        float w11 = gu * gv, w12 = gu * dv, w21 = du * gv, w22 = du * dv;

        long long o11 = (((iu1 << 7) + iv1) << 7) + iwb;
        long long o12 = (((iu1 << 7) + iv2) << 7) + iwb;
        long long o21 = (((iu2 << 7) + iv1) << 7) + iwb;
        long long o22 = (((iu2 << 7) + iv2) << 7) + iwb;

        uint2 L11 = gb8[o11], H11 = gb8[o11 + 1];
        uint2 L12 = gb8[o12], H12 = gb8[o12 + 1];
        uint2 L21 = gb8[o21], H21 = gb8[o21 + 1];
        uint2 L22 = gb8[o22], H22 = gb8[o22 + 1];

        auto ch = [](const uint2& q, int k) -> float {
            unsigned short us = (k == 0) ? (unsigned short)(q.x & 0xffff)
                            : (k == 1) ? (unsigned short)(q.x >> 16)
                                       : (unsigned short)(q.y & 0xffff);
            return __half2float(__ushort_as_half(us));
        };

        float o[3];
        #pragma unroll
        for (int k = 0; k < 3; ++k) {
            float a11 = lo ? ch(L11, k) : ch(H11, k);
            float a12 = lo ? ch(L12, k) : ch(H12, k);
            float a21 = lo ? ch(L21, k) : ch(H21, k);
            float a22 = lo ? ch(L22, k) : ch(H22, k);
            o[k] = w11 * (gw * a11 + dw * ch(H11, k))
                 + w12 * (gw * a12 + dw * ch(H12, k))
                 + w21 * (gw * a21 + dw * ch(H21, k))
                 + w22 * (gw * a22 + dw * ch(H22, k));
        }

        float* op = out + (long long)t * 3;
        op[0] = o[0]; op[1] = o[1]; op[2] = o[2];
    }
}

// ---------------- fallback (R3): f32 broadcast scan, no workspace -----------
__global__ __launch_bounds__(256) void trilerp_pair_kernel(
    const float* __restrict__ vel, const float* __restrict__ pts,
    const float* __restrict__ bb, float* __restrict__ out,
    int N, int nchunk)
{
    int bid  = blockIdx.x;
    int slab = bid & (NSLAB - 1);
    int t    = bid >> 3;
    int c    = t % nchunk;
    int b    = t / nchunk;
    int n = c * 256 + threadIdx.x;
    if (n >= N) return;

    float bx0 = bb[0], bx1 = bb[1];
    float by0 = bb[2], by1 = bb[3];
    float bz0 = bb[4], bz1 = bb[5];
    long long pi = (long long)b * N + n;
    const float* p = pts + pi * 3;
    float px = p[0], py = p[1], pz = p[2];
    const float Gm1 = (float)(G - 1);
    float u = (px - bx0) / (bx1 - bx0) * Gm1;
    float fu = fminf(fmaxf(floorf(u), 0.f), Gm1);
    int iu1 = (int)fu;
    if ((iu1 >> 4) != slab) return;
    float v = (py - by0) / (by1 - by0) * Gm1;
    float w = (pz - bz0) / (bz1 - bz0) * Gm1;
    float fv = fminf(fmaxf(floorf(v), 0.f), Gm1);
    float fw = fminf(fmaxf(floorf(w), 0.f), Gm1);
    float du = u - fu, dv = v - fv, dw = w - fw;
    float gu = fu + 1.0f - u, gv = fv + 1.0f - v, gw = fw + 1.0f - w;
    int iv1 = (int)fv, iw1 = (int)fw;
    int iu2 = min(iu1 + 1, G - 1);
    int iv2 = min(iv1 + 1, G - 1);
    int iwb = min(iw1, G - 2);
    bool lo = (iw1 <= G - 2);
    float w11 = gu * gv, w12 = gu * dv, w21 = du * gv, w22 = du * dv;
    const float* vb = vel + (long long)b * 3 * G3;
    long long o11 = (long long)((iu1 << 7) + iv1) * G + iwb;
    long long o12 = (long long)((iu1 << 7) + iv2) * G + iwb;
    long long o21 = (long long)((iu2 << 7) + iv1) * G + iwb;
    long long o22 = (long long)((iu2 << 7) + iv2) * G + iwb;
    float o[3];
    #pragma unroll
    for (int chn = 0; chn < 3; ++chn) {
        const float* vc = vb + (long long)chn * G3;
        float2 p11 = *reinterpret_cast<const float2*>(vc + o11);
        float2 p12 = *reinterpret_cast<const float2*>(vc + o12);
        float2 p21 = *reinterpret_cast<const float2*>(vc + o21);
        float2 p22 = *reinterpret_cast<const float2*>(vc + o22);
        float a11 = lo ? p11.x : p11.y;
        float a12 = lo ? p12.x : p12.y;
        float a21 = lo ? p21.x : p21.y;
        float a22 = lo ? p22.x : p22.y;
        o[chn] = w11 * (gw * a11 + dw * p11.y)
               + w12 * (gw * a12 + dw * p12.y)
               + w21 * (gw * a21 + dw * p21.y)
               + w22 * (gw * a22 + dw * p22.y);
    }
    float* op = out + pi * 3;
    op[0] = o[0]; op[1] = o[1]; op[2] = o[2];
}

extern "C" void kernel_launch(void* const* d_in, const int* in_sizes, int n_in,
                              void* d_out, int out_size, void* d_ws, size_t ws_size,
                              hipStream_t stream) {
    const float* vel = (const float*)d_in[0];
    const float* pts = (const float*)d_in[1];
    const float* bb  = (const float*)d_in[2];
    float* out = (float*)d_out;

    int B = (int)(in_sizes[0] / (3 * G3));       // 16
    int N = in_sizes[1] / (3 * B);               // 200000
    int total = B * N;                           // 3.2M
    int nbins = B * NBU * NBV;                   // 16384

    auto align256 = [](size_t x) { return (x + 255) & ~(size_t)255; };
    size_t off_grid = 0;
    size_t sz_grid  = (size_t)B * G3 * 8;                    // 268 MB
    size_t off_cnt  = align256(off_grid + sz_grid);
    size_t sz_cnt   = (size_t)nbins * 4;
    size_t off_base = align256(off_cnt + sz_cnt);
    size_t sz_base  = (size_t)(nbins + 1) * 4;
    size_t off_cur  = align256(off_base + sz_base);
    size_t sz_cur   = (size_t)nbins * 4;
    size_t off_pay  = align256(off_cur + sz_cur);
    size_t sz_pay   = (size_t)total * 16;                    // 51 MB
    size_t need     = off_pay + sz_pay;                      // ~320 MB

    if (ws_size >= need && B <= 64 && (nbins % 1024) == 0) {
        uint2*  grid8   = (uint2*)((char*)d_ws + off_grid);
        int*    cnt     = (int*)((char*)d_ws + off_cnt);
        int*    base    = (int*)((char*)d_ws + off_base);
        int*    cursor  = (int*)((char*)d_ws + off_cur);
        float4* payload = (float4*)((char*)d_ws + off_pay);

        hipMemsetAsync(cnt, 0, sz_cnt, stream);

        long long rblocks = (long long)B * (G3 / 4) / 256;   // 32768
        repack_kernel<<<(int)rblocks, 256, 0, stream>>>(vel, grid8);

        int pblocks = (total + 255) / 256;                   // 12500
        count_kernel<<<pblocks, 256, 0, stream>>>(pts, bb, cnt, N, total);
        scan_kernel<<<1, 1024, 0, stream>>>(cnt, base, cursor, nbins);
        scatter_kernel<<<pblocks, 256, 0, stream>>>(pts, bb, cursor, payload, N, total);

        trilerp_binned_kernel<<<nbins, 128, 0, stream>>>(grid8, base, payload, out);
    } else {
        int nchunk = (N + 255) / 256;
        long long blocks = (long long)B * nchunk * NSLAB;
        trilerp_pair_kernel<<<(int)blocks, 256, 0, stream>>>(vel, pts, bb, out, N, nchunk);
    }
}

// Round 8
// 342.990 us; speedup vs baseline: 2.2451x; 2.2451x over previous
//
#include <hip/hip_runtime.h>
#include <hip/hip_fp16.h>

// Trilinear grid interpolation — fp16 repack + uv-bin + LDS-staged gather.
//   velocity: [B, 3, G, G, G] f32, points: [B, N, 3] f32, bb: [3,2] f32
//   out: [B, N, 3] f32
//
// Model (R1-R6, validated): global gathers cost ~1 txn/lane (L1 hit) and
// ~5 cyc/line miss; R4's 330us == 12.7 lines/pt x 5cyc exactly. L1-residency
// via binning can't work (6 resident blocks share 32KB L1). But LDS serves
// a 64-lane gather in ONE ds_read — so: bin points by (iu/4, iv/4), stage
// each bin's packed region (5x5x128 cells = 25.6KB) into LDS from the
// XCD-pinned L2-resident slab, gather from LDS.
// R6 scatter lesson: no per-point device atomics; no cross-XCD partial-line
// payload writes. Fix: 4096-pt window blocks + LDS histogram -> one global
// atomic per (window,bin); payload runs of ~4 (full 64B lines).

constexpr int G = 128;
constexpr long long G3 = (long long)G * G * G;
constexpr int NSLAB = 8;            // == #XCDs
constexpr int NBU = 32, NBV = 32;   // 4x4-cell uv bins; 1024 bins/batch
constexpr int WINPTS = 4096;        // points per count/scatter window block

// ---------------- repack: [B,3,G3] f32 -> [B,G3] 8B cells (3xfp16+pad) ------
__global__ __launch_bounds__(256) void repack_kernel(
    const float* __restrict__ vel, uint2* __restrict__ grid8)
{
    long long t = (long long)blockIdx.x * 256 + threadIdx.x;  // 4-cell unit
    long long cell4 = t * 4;
    int bw = (int)(cell4 / G3);
    int ci = (int)(cell4 % G3);
    long long vbase = ((long long)bw * 3) * G3;

    float4 v0 = *reinterpret_cast<const float4*>(vel + vbase + ci);
    float4 v1 = *reinterpret_cast<const float4*>(vel + vbase + G3 + ci);
    float4 v2 = *reinterpret_cast<const float4*>(vel + vbase + 2 * G3 + ci);

    auto pk = [](float a, float b) -> unsigned int {
        unsigned int ua = __half_as_ushort(__float2half(a));
        unsigned int ub = __half_as_ushort(__float2half(b));
        return ua | (ub << 16);
    };
    auto pq = [](float c) -> unsigned int {
        return (unsigned int)__half_as_ushort(__float2half(c));
    };

    uint4 d0, d1;
    d0.x = pk(v0.x, v1.x); d0.y = pq(v2.x);
    d0.z = pk(v0.y, v1.y); d0.w = pq(v2.y);
    d1.x = pk(v0.z, v1.z); d1.y = pq(v2.z);
    d1.z = pk(v0.w, v1.w); d1.w = pq(v2.w);

    uint4* dst = reinterpret_cast<uint4*>(grid8 + (long long)bw * G3 + ci);
    dst[0] = d0;
    dst[1] = d1;
}

__device__ inline int bin_of(float px, float py, const float* bb, float Gm1) {
    float u = (px - bb[0]) / (bb[1] - bb[0]) * Gm1;
    float v = (py - bb[2]) / (bb[3] - bb[2]) * Gm1;
    int iu1 = (int)fminf(fmaxf(floorf(u), 0.f), Gm1);
    int iv1 = (int)fminf(fmaxf(floorf(v), 0.f), Gm1);
    return ((iu1 >> 2) << 5) | (iv1 >> 2);     // bin within batch, 0..1023
}

// ---------------- pass 1a: per-bin counts (window LDS histogram) ------------
__global__ __launch_bounds__(256) void count_kernel(
    const float* __restrict__ pts, const float* __restrict__ bb,
    int* __restrict__ cnt, int N, int nwin)
{
    __shared__ int h[NBU * NBV];
    int b = blockIdx.x / nwin;
    int w = blockIdx.x % nwin;
    for (int i = threadIdx.x; i < NBU * NBV; i += 256) h[i] = 0;
    __syncthreads();

    const float Gm1 = (float)(G - 1);
    long long pbase = (long long)b * N;
    int n0 = w * WINPTS;
    #pragma unroll
    for (int it = 0; it < WINPTS / 256; ++it) {
        int n = n0 + it * 256 + threadIdx.x;
        if (n < N) {
            const float* p = pts + (pbase + n) * 3;
            atomicAdd(&h[bin_of(p[0], p[1], bb, Gm1)], 1);
        }
    }
    __syncthreads();
    for (int i = threadIdx.x; i < NBU * NBV; i += 256)
        if (h[i]) atomicAdd(&cnt[b * NBU * NBV + i], h[i]);
}

// ---------------- pass 1b: exclusive scan over nbins (one block) ------------
__global__ __launch_bounds__(1024) void scan_kernel(
    const int* __restrict__ cnt, int* __restrict__ base,
    int* __restrict__ cursor, int nbins)
{
    __shared__ int sh[1024];
    int t = threadIdx.x;
    int per = nbins / 1024;
    int local[64];
    int s = 0;
    for (int j = 0; j < per; ++j) { local[j] = cnt[t * per + j]; s += local[j]; }
    sh[t] = s;
    __syncthreads();
    for (int off = 1; off < 1024; off <<= 1) {
        int v = (t >= off) ? sh[t - off] : 0;
        __syncthreads();
        sh[t] += v;
        __syncthreads();
    }
    int run = sh[t] - s;
    for (int j = 0; j < per; ++j) {
        base[t * per + j] = run;
        cursor[t * per + j] = run;
        run += local[j];
    }
    if (t == 1023) base[nbins] = sh[1023];
}

// ---------------- pass 1c: scatter payload (window two-phase) ----------------
__global__ __launch_bounds__(256) void scatter_kernel(
    const float* __restrict__ pts, const float* __restrict__ bb,
    int* __restrict__ cursor, float4* __restrict__ payload,
    int N, int nwin)
{
    __shared__ int h[NBU * NBV];
    __shared__ int basel[NBU * NBV];
    int b = blockIdx.x / nwin;
    int w = blockIdx.x % nwin;
    for (int i = threadIdx.x; i < NBU * NBV; i += 256) h[i] = 0;
    __syncthreads();

    const float Gm1 = (float)(G - 1);
    long long pbase = (long long)b * N;
    int n0 = w * WINPTS;

    // phase 1: window histogram
    #pragma unroll
    for (int it = 0; it < WINPTS / 256; ++it) {
        int n = n0 + it * 256 + threadIdx.x;
        if (n < N) {
            const float* p = pts + (pbase + n) * 3;
            atomicAdd(&h[bin_of(p[0], p[1], bb, Gm1)], 1);
        }
    }
    __syncthreads();
    // claim global ranges: one device atomic per nonzero bin
    for (int i = threadIdx.x; i < NBU * NBV; i += 256)
        if (h[i]) basel[i] = atomicAdd(&cursor[b * NBU * NBV + i], h[i]);
    __syncthreads();
    // phase 2: re-read (L2-hot), rank via LDS atomics, write payload
    float bx0 = bb[0], bx1 = bb[1];
    float by0 = bb[2], by1 = bb[3];
    float bz0 = bb[4], bz1 = bb[5];
    #pragma unroll
    for (int it = 0; it < WINPTS / 256; ++it) {
        int n = n0 + it * 256 + threadIdx.x;
        if (n < N) {
            const float* p = pts + (pbase + n) * 3;
            float px = p[0], py = p[1], pz = p[2];
            float u = (px - bx0) / (bx1 - bx0) * Gm1;
            float v = (py - by0) / (by1 - by0) * Gm1;
            float wz = (pz - bz0) / (bz1 - bz0) * Gm1;
            int iu1 = (int)fminf(fmaxf(floorf(u), 0.f), Gm1);
            int iv1 = (int)fminf(fmaxf(floorf(v), 0.f), Gm1);
            int bin = ((iu1 >> 2) << 5) | (iv1 >> 2);
            int pos = atomicAdd(&basel[bin], 1);
            payload[pos] = make_float4(u, v, wz, __int_as_float((int)(pbase + n)));
        }
    }
}

// ---------------- pass 2: LDS-staged binned gather ----------------
__global__ __launch_bounds__(256) void trilerp_lds_kernel(
    const uint2* __restrict__ grid8,     // [B,G3]
    const int* __restrict__ base,        // [nbins+1]
    const float4* __restrict__ payload,  // [B*N] {u,v,w,idx}
    float* __restrict__ out)             // [B,N,3]
{
    // blockIdx.x = slab + 8*(b*128 + (iu4&3)*32 + iv4); blockIdx%8 == XCD slab
    __shared__ uint2 cells[5 * 5 * G];   // 25.6 KB

    int x = blockIdx.x;
    int slab = x & (NSLAB - 1);
    int rest = x >> 3;
    int b    = rest >> 7;
    int r2   = rest & 127;
    int iu4  = (slab << 2) | (r2 >> 5);
    int iv4  = r2 & 31;
    int bin  = (b * NBU + iu4) * NBV + iv4;

    int s = base[bin], e = base[bin + 1];
    if (s == e) return;

    int u0 = iu4 << 2, v0 = iv4 << 2;
    const uint2* gb8 = grid8 + (long long)b * G3;

    // stage 5x5 rows x 128 cells, coalesced (consecutive threads -> consecutive iw)
    for (int k = 0; k < 13; ++k) {
        int idx = threadIdx.x + k * 256;
        if (idx < 5 * 5 * G) {
            int row = idx >> 7;            // 0..24
            int iw  = idx & 127;
            int gu  = min(u0 + row / 5, G - 1);
            int gv  = min(v0 + row % 5, G - 1);
            cells[idx] = gb8[(((long long)(gu << 7) + gv) << 7) + iw];
        }
    }
    __syncthreads();

    const float Gm1 = (float)(G - 1);

    auto ch = [](const uint2& q, int k) -> float {
        unsigned short us = (k == 0) ? (unsigned short)(q.x & 0xffff)
                        : (k == 1) ? (unsigned short)(q.x >> 16)
                                   : (unsigned short)(q.y & 0xffff);
        return __half2float(__ushort_as_half(us));
    };

    for (int i = s + (int)threadIdx.x; i < e; i += 256) {
        float4 pl = payload[i];
        float u = pl.x, v = pl.y, w = pl.z;
        int t = __float_as_int(pl.w);

        float fu = fminf(fmaxf(floorf(u), 0.f), Gm1);
        float fv = fminf(fmaxf(floorf(v), 0.f), Gm1);
        float fw = fminf(fmaxf(floorf(w), 0.f), Gm1);

        float du = u - fu, dv = v - fv, dw = w - fw;   // frac
        float gu = fu + 1.0f - u;                      // gfrac
        float gv = fv + 1.0f - v;
        float gw = fw + 1.0f - w;

        int iu1 = (int)fu, iv1 = (int)fv, iw1 = (int)fw;
        int iu2 = min(iu1 + 1, G - 1);
        int iv2 = min(iv1 + 1, G - 1);
        int iwb = min(iw1, G - 2);
        bool lo = (iw1 <= G - 2);

        float w11 = gu * gv, w12 = gu * dv, w21 = du * gv, w22 = du * dv;

        int r11 = ((iu1 - u0) * 5 + (iv1 - v0)) << 7;
        int r12 = ((iu1 - u0) * 5 + (iv2 - v0)) << 7;
        int r21 = ((iu2 - u0) * 5 + (iv1 - v0)) << 7;
        int r22 = ((iu2 - u0) * 5 + (iv2 - v0)) << 7;

        uint2 L11 = cells[r11 + iwb], H11 = cells[r11 + iwb + 1];
        uint2 L12 = cells[r12 + iwb], H12 = cells[r12 + iwb + 1];
        uint2 L21 = cells[r21 + iwb], H21 = cells[r21 + iwb + 1];
        uint2 L22 = cells[r22 + iwb], H22 = cells[r22 + iwb + 1];

        float o[3];
        #pragma unroll
        for (int k = 0; k < 3; ++k) {
            float a11 = lo ? ch(L11, k) : ch(H11, k);
            float a12 = lo ? ch(L12, k) : ch(H12, k);
            float a21 = lo ? ch(L21, k) : ch(H21, k);
            float a22 = lo ? ch(L22, k) : ch(H22, k);
            o[k] = w11 * (gw * a11 + dw * ch(H11, k))
                 + w12 * (gw * a12 + dw * ch(H12, k))
                 + w21 * (gw * a21 + dw * ch(H21, k))
                 + w22 * (gw * a22 + dw * ch(H22, k));
        }

        float* op = out + (long long)t * 3;
        op[0] = o[0]; op[1] = o[1]; op[2] = o[2];
    }
}

// ---------------- fallback (R3): f32 broadcast scan, no workspace -----------
__global__ __launch_bounds__(256) void trilerp_pair_kernel(
    const float* __restrict__ vel, const float* __restrict__ pts,
    const float* __restrict__ bb, float* __restrict__ out,
    int N, int nchunk)
{
    int bid  = blockIdx.x;
    int slab = bid & (NSLAB - 1);
    int t    = bid >> 3;
    int c    = t % nchunk;
    int b    = t / nchunk;
    int n = c * 256 + threadIdx.x;
    if (n >= N) return;

    float bx0 = bb[0], bx1 = bb[1];
    float by0 = bb[2], by1 = bb[3];
    float bz0 = bb[4], bz1 = bb[5];
    long long pi = (long long)b * N + n;
    const float* p = pts + pi * 3;
    float px = p[0], py = p[1], pz = p[2];
    const float Gm1 = (float)(G - 1);
    float u = (px - bx0) / (bx1 - bx0) * Gm1;
    float fu = fminf(fmaxf(floorf(u), 0.f), Gm1);
    int iu1 = (int)fu;
    if ((iu1 >> 4) != slab) return;
    float v = (py - by0) / (by1 - by0) * Gm1;
    float w = (pz - bz0) / (bz1 - bz0) * Gm1;
    float fv = fminf(fmaxf(floorf(v), 0.f), Gm1);
    float fw = fminf(fmaxf(floorf(w), 0.f), Gm1);
    float du = u - fu, dv = v - fv, dw = w - fw;
    float gu = fu + 1.0f - u, gv = fv + 1.0f - v, gw = fw + 1.0f - w;
    int iv1 = (int)fv, iw1 = (int)fw;
    int iu2 = min(iu1 + 1, G - 1);
    int iv2 = min(iv1 + 1, G - 1);
    int iwb = min(iw1, G - 2);
    bool lo = (iw1 <= G - 2);
    float w11 = gu * gv, w12 = gu * dv, w21 = du * gv, w22 = du * dv;
    const float* vb = vel + (long long)b * 3 * G3;
    long long o11 = (long long)((iu1 << 7) + iv1) * G + iwb;
    long long o12 = (long long)((iu1 << 7) + iv2) * G + iwb;
    long long o21 = (long long)((iu2 << 7) + iv1) * G + iwb;
    long long o22 = (long long)((iu2 << 7) + iv2) * G + iwb;
    float o[3];
    #pragma unroll
    for (int chn = 0; chn < 3; ++chn) {
        const float* vc = vb + (long long)chn * G3;
        float2 p11 = *reinterpret_cast<const float2*>(vc + o11);
        float2 p12 = *reinterpret_cast<const float2*>(vc + o12);
        float2 p21 = *reinterpret_cast<const float2*>(vc + o21);
        float2 p22 = *reinterpret_cast<const float2*>(vc + o22);
        float a11 = lo ? p11.x : p11.y;
        float a12 = lo ? p12.x : p12.y;
        float a21 = lo ? p21.x : p21.y;
        float a22 = lo ? p22.x : p22.y;
        o[chn] = w11 * (gw * a11 + dw * p11.y)
               + w12 * (gw * a12 + dw * p12.y)
               + w21 * (gw * a21 + dw * p21.y)
               + w22 * (gw * a22 + dw * p22.y);
    }
    float* op = out + pi * 3;
    op[0] = o[0]; op[1] = o[1]; op[2] = o[2];
}

extern "C" void kernel_launch(void* const* d_in, const int* in_sizes, int n_in,
                              void* d_out, int out_size, void* d_ws, size_t ws_size,
                              hipStream_t stream) {
    const float* vel = (const float*)d_in[0];
    const float* pts = (const float*)d_in[1];
    const float* bb  = (const float*)d_in[2];
    float* out = (float*)d_out;

    int B = (int)(in_sizes[0] / (3 * G3));       // 16
    int N = in_sizes[1] / (3 * B);               // 200000
    int total = B * N;                           // 3.2M
    int nbins = B * NBU * NBV;                   // 16384
    int nwin  = (N + WINPTS - 1) / WINPTS;       // 49

    auto align256 = [](size_t x) { return (x + 255) & ~(size_t)255; };
    size_t off_grid = 0;
    size_t sz_grid  = (size_t)B * G3 * 8;                    // 268 MB
    size_t off_cnt  = align256(off_grid + sz_grid);
    size_t sz_cnt   = (size_t)nbins * 4;
    size_t off_base = align256(off_cnt + sz_cnt);
    size_t sz_base  = (size_t)(nbins + 1) * 4;
    size_t off_cur  = align256(off_base + sz_base);
    size_t sz_cur   = (size_t)nbins * 4;
    size_t off_pay  = align256(off_cur + sz_cur);
    size_t sz_pay   = (size_t)total * 16;                    // 51 MB
    size_t need     = off_pay + sz_pay;                      // ~320 MB

    if (ws_size >= need && B <= 64 && (nbins % 1024) == 0) {
        uint2*  grid8   = (uint2*)((char*)d_ws + off_grid);
        int*    cnt     = (int*)((char*)d_ws + off_cnt);
        int*    base    = (int*)((char*)d_ws + off_base);
        int*    cursor  = (int*)((char*)d_ws + off_cur);
        float4* payload = (float4*)((char*)d_ws + off_pay);

        hipMemsetAsync(cnt, 0, sz_cnt, stream);

        long long rblocks = (long long)B * (G3 / 4) / 256;   // 32768
        repack_kernel<<<(int)rblocks, 256, 0, stream>>>(vel, grid8);

        count_kernel<<<B * nwin, 256, 0, stream>>>(pts, bb, cnt, N, nwin);
        scan_kernel<<<1, 1024, 0, stream>>>(cnt, base, cursor, nbins);
        scatter_kernel<<<B * nwin, 256, 0, stream>>>(pts, bb, cursor, payload, N, nwin);

        trilerp_lds_kernel<<<nbins, 256, 0, stream>>>(grid8, base, payload, out);
    } else {
        int nchunk = (N + 255) / 256;
        long long blocks = (long long)B * nchunk * NSLAB;
        trilerp_pair_kernel<<<(int)blocks, 256, 0, stream>>>(vel, pts, bb, out, N, nchunk);
    }
}

// Round 9
// 260.578 us; speedup vs baseline: 2.9552x; 1.3163x over previous
//
#include <hip/hip_runtime.h>

// Trilinear grid interpolation — uv-bin + fused f32 LDS-staged gather (no repack).
//   velocity: [B, 3, G, G, G] f32, points: [B, N, 3] f32, bb: [3,2] f32
//   out: [B, N, 3] f32
//
// Evidence R1-R7: gather is L1-miss bound unless served from LDS; a
// materialized repack pass costs 670MB + 420MB re-read (grid evicted from L2
// between passes). R8: the binned gather stages each bin's 5x5x128 f32
// region straight from the original velocity into LDS (layout conversion for
// free). Per-XCD iu4-band ordering keeps the 1MB active band L2-resident ->
// velocity crosses HBM ~once. Binning: count -> scan -> scatter {u,v,w,idx}.

constexpr int G = 128;
constexpr long long G3 = (long long)G * G * G;   // 1<<21
constexpr int NSLAB = 8;            // == #XCDs
constexpr int NBU = 32, NBV = 32;   // 4x4-cell uv bins; 1024 bins/batch
constexpr int WINPTS = 8192;        // points per count/scatter window block
constexpr int RS = 132;             // LDS row stride (floats): 16B-aligned rows

__device__ inline int bin_of(float px, float py, const float* bb, float Gm1) {
    float u = (px - bb[0]) / (bb[1] - bb[0]) * Gm1;
    float v = (py - bb[2]) / (bb[3] - bb[2]) * Gm1;
    int iu1 = (int)fminf(fmaxf(floorf(u), 0.f), Gm1);
    int iv1 = (int)fminf(fmaxf(floorf(v), 0.f), Gm1);
    return ((iu1 >> 2) << 5) | (iv1 >> 2);     // bin within batch, 0..1023
}

// ---------------- pass 1a: per-bin counts (window LDS histogram) ------------
__global__ __launch_bounds__(256) void count_kernel(
    const float* __restrict__ pts, const float* __restrict__ bb,
    int* __restrict__ cnt, int N, int nwin)
{
    __shared__ int h[NBU * NBV];
    int b = blockIdx.x / nwin;
    int w = blockIdx.x % nwin;
    for (int i = threadIdx.x; i < NBU * NBV; i += 256) h[i] = 0;
    __syncthreads();

    const float Gm1 = (float)(G - 1);
    long long pbase = (long long)b * N;
    int n0 = w * WINPTS;
    for (int it = 0; it < WINPTS / 256; ++it) {
        int n = n0 + it * 256 + threadIdx.x;
        if (n < N) {
            const float* p = pts + (pbase + n) * 3;
            atomicAdd(&h[bin_of(p[0], p[1], bb, Gm1)], 1);
        }
    }
    __syncthreads();
    for (int i = threadIdx.x; i < NBU * NBV; i += 256)
        if (h[i]) atomicAdd(&cnt[b * NBU * NBV + i], h[i]);
}

// ---------------- pass 1b: exclusive scan over nbins (one block) ------------
__global__ __launch_bounds__(1024) void scan_kernel(
    const int* __restrict__ cnt, int* __restrict__ base,
    int* __restrict__ cursor, int nbins)
{
    __shared__ int sh[1024];
    int t = threadIdx.x;
    int per = nbins / 1024;
    int local[64];
    int s = 0;
    for (int j = 0; j < per; ++j) { local[j] = cnt[t * per + j]; s += local[j]; }
    sh[t] = s;
    __syncthreads();
    for (int off = 1; off < 1024; off <<= 1) {
        int v = (t >= off) ? sh[t - off] : 0;
        __syncthreads();
        sh[t] += v;
        __syncthreads();
    }
    int run = sh[t] - s;
    for (int j = 0; j < per; ++j) {
        base[t * per + j] = run;
        cursor[t * per + j] = run;
        run += local[j];
    }
    if (t == 1023) base[nbins] = sh[1023];
}

// ---------------- pass 1c: scatter payload (window two-phase) ----------------
__global__ __launch_bounds__(256) void scatter_kernel(
    const float* __restrict__ pts, const float* __restrict__ bb,
    int* __restrict__ cursor, float4* __restrict__ payload,
    int N, int nwin)
{
    __shared__ int h[NBU * NBV];
    __shared__ int basel[NBU * NBV];
    int b = blockIdx.x / nwin;
    int w = blockIdx.x % nwin;
    for (int i = threadIdx.x; i < NBU * NBV; i += 256) h[i] = 0;
    __syncthreads();

    const float Gm1 = (float)(G - 1);
    long long pbase = (long long)b * N;
    int n0 = w * WINPTS;

    for (int it = 0; it < WINPTS / 256; ++it) {
        int n = n0 + it * 256 + threadIdx.x;
        if (n < N) {
            const float* p = pts + (pbase + n) * 3;
            atomicAdd(&h[bin_of(p[0], p[1], bb, Gm1)], 1);
        }
    }
    __syncthreads();
    for (int i = threadIdx.x; i < NBU * NBV; i += 256)
        if (h[i]) basel[i] = atomicAdd(&cursor[b * NBU * NBV + i], h[i]);
    __syncthreads();

    float bx0 = bb[0], bx1 = bb[1];
    float by0 = bb[2], by1 = bb[3];
    float bz0 = bb[4], bz1 = bb[5];
    for (int it = 0; it < WINPTS / 256; ++it) {
        int n = n0 + it * 256 + threadIdx.x;
        if (n < N) {
            const float* p = pts + (pbase + n) * 3;
            float px = p[0], py = p[1], pz = p[2];
            float u = (px - bx0) / (bx1 - bx0) * Gm1;
            float v = (py - by0) / (by1 - by0) * Gm1;
            float wz = (pz - bz0) / (bz1 - bz0) * Gm1;
            int iu1 = (int)fminf(fmaxf(floorf(u), 0.f), Gm1);
            int iv1 = (int)fminf(fmaxf(floorf(v), 0.f), Gm1);
            int bin = ((iu1 >> 2) << 5) | (iv1 >> 2);
            int pos = atomicAdd(&basel[bin], 1);
            payload[pos] = make_float4(u, v, wz, __int_as_float((int)(pbase + n)));
        }
    }
}

// ---------------- pass 2: binned gather, f32 LDS staging ----------------
__global__ __launch_bounds__(256) void trilerp_lds_kernel(
    const float* __restrict__ vel,       // [B,3,G,G,G]
    const int* __restrict__ base,        // [nbins+1]
    const float4* __restrict__ payload,  // [B*N] {u,v,w,idx}
    float* __restrict__ out)             // [B,N,3]
{
    // blockIdx.x = slab + 8*(b*128 + j*32 + iv4);  iu4 = slab*4 + j
    // -> blockIdx%8 == XCD slab; per-XCD order: iv4 inner, iu4-band next
    __shared__ float s_vel[3 * 25 * RS];   // 39.6 KB

    int x = blockIdx.x;
    int slab = x & (NSLAB - 1);
    int rest = x >> 3;
    int b    = rest >> 7;
    int r2   = rest & 127;
    int iu4  = (slab << 2) | (r2 >> 5);
    int iv4  = r2 & 31;
    int bin  = (b * NBU + iu4) * NBV + iv4;

    int s = base[bin], e = base[bin + 1];

    int u0 = iu4 << 2, v0 = iv4 << 2;

    // stage 3 channels x 25 rows x 128 cells as float4s, coalesced
    // unit idx in [0,2400): f4 = idx&31, ru = idx>>5; ch = ru/25, r = ru%25
    for (int k = 0; k < 10; ++k) {
        int idx = (int)threadIdx.x + k * 256;
        if (idx < 2400) {
            int f4 = idx & 31;
            int ru = idx >> 5;
            int ch = ru / 25;
            int r  = ru - ch * 25;
            int gu = min(u0 + r / 5, G - 1);
            int gv = min(v0 + (r - (r / 5) * 5), G - 1);
            long long src = (((long long)b * 3 + ch) << 21) + ((long long)gu << 14) + (gv << 7) + (f4 << 2);
            float4 val = *reinterpret_cast<const float4*>(vel + src);
            *reinterpret_cast<float4*>(&s_vel[(ch * 25 + r) * RS + (f4 << 2)]) = val;
        }
    }
    __syncthreads();

    if (s == e) return;
    const float Gm1 = (float)(G - 1);

    for (int i = s + (int)threadIdx.x; i < e; i += 256) {
        float4 pl = payload[i];
        float u = pl.x, v = pl.y, w = pl.z;
        int t = __float_as_int(pl.w);

        float fu = fminf(fmaxf(floorf(u), 0.f), Gm1);
        float fv = fminf(fmaxf(floorf(v), 0.f), Gm1);
        float fw = fminf(fmaxf(floorf(w), 0.f), Gm1);

        float du = u - fu, dv = v - fv, dw = w - fw;   // frac
        float gu = fu + 1.0f - u;                      // gfrac
        float gv = fv + 1.0f - v;
        float gw = fw + 1.0f - w;

        int iu1 = (int)fu, iv1 = (int)fv, iw1 = (int)fw;
        int iu2 = min(iu1 + 1, G - 1);
        int iv2 = min(iv1 + 1, G - 1);
        int iwb = min(iw1, G - 2);
        bool lo = (iw1 <= G - 2);

        float w11 = gu * gv, w12 = gu * dv, w21 = du * gv, w22 = du * dv;

        int du1 = iu1 - u0, dv1 = iv1 - v0;
        int du2 = iu2 - u0, dv2 = iv2 - v0;

        float o[3];
        #pragma unroll
        for (int ch = 0; ch < 3; ++ch) {
            int rb = ch * 25;
            const float* c11 = &s_vel[(rb + du1 * 5 + dv1) * RS + iwb];
            const float* c12 = &s_vel[(rb + du1 * 5 + dv2) * RS + iwb];
            const float* c21 = &s_vel[(rb + du2 * 5 + dv1) * RS + iwb];
            const float* c22 = &s_vel[(rb + du2 * 5 + dv2) * RS + iwb];
            float2 p11 = *reinterpret_cast<const float2*>(c11);
            float2 p12 = *reinterpret_cast<const float2*>(c12);
            float2 p21 = *reinterpret_cast<const float2*>(c21);
            float2 p22 = *reinterpret_cast<const float2*>(c22);
            float a11 = lo ? p11.x : p11.y;
            float a12 = lo ? p12.x : p12.y;
            float a21 = lo ? p21.x : p21.y;
            float a22 = lo ? p22.x : p22.y;
            o[ch] = w11 * (gw * a11 + dw * p11.y)
                  + w12 * (gw * a12 + dw * p12.y)
                  + w21 * (gw * a21 + dw * p21.y)
                  + w22 * (gw * a22 + dw * p22.y);
        }

        float* op = out + (long long)t * 3;
        op[0] = o[0]; op[1] = o[1]; op[2] = o[2];
    }
}

// ---------------- fallback (R3): f32 broadcast scan, no workspace -----------
__global__ __launch_bounds__(256) void trilerp_pair_kernel(
    const float* __restrict__ vel, const float* __restrict__ pts,
    const float* __restrict__ bb, float* __restrict__ out,
    int N, int nchunk)
{
    int bid  = blockIdx.x;
    int slab = bid & (NSLAB - 1);
    int t    = bid >> 3;
    int c    = t % nchunk;
    int b    = t / nchunk;
    int n = c * 256 + threadIdx.x;
    if (n >= N) return;

    float bx0 = bb[0], bx1 = bb[1];
    float by0 = bb[2], by1 = bb[3];
    float bz0 = bb[4], bz1 = bb[5];
    long long pi = (long long)b * N + n;
    const float* p = pts + pi * 3;
    float px = p[0], py = p[1], pz = p[2];
    const float Gm1 = (float)(G - 1);
    float u = (px - bx0) / (bx1 - bx0) * Gm1;
    float fu = fminf(fmaxf(floorf(u), 0.f), Gm1);
    int iu1 = (int)fu;
    if ((iu1 >> 4) != slab) return;
    float v = (py - by0) / (by1 - by0) * Gm1;
    float w = (pz - bz0) / (bz1 - bz0) * Gm1;
    float fv = fminf(fmaxf(floorf(v), 0.f), Gm1);
    float fw = fminf(fmaxf(floorf(w), 0.f), Gm1);
    float du = u - fu, dv = v - fv, dw = w - fw;
    float gu = fu + 1.0f - u, gv = fv + 1.0f - v, gw = fw + 1.0f - w;
    int iv1 = (int)fv, iw1 = (int)fw;
    int iu2 = min(iu1 + 1, G - 1);
    int iv2 = min(iv1 + 1, G - 1);
    int iwb = min(iw1, G - 2);
    bool lo = (iw1 <= G - 2);
    float w11 = gu * gv, w12 = gu * dv, w21 = du * gv, w22 = du * dv;
    const float* vb = vel + (long long)b * 3 * G3;
    long long o11 = (long long)((iu1 << 7) + iv1) * G + iwb;
    long long o12 = (long long)((iu1 << 7) + iv2) * G + iwb;
    long long o21 = (long long)((iu2 << 7) + iv1) * G + iwb;
    long long o22 = (long long)((iu2 << 7) + iv2) * G + iwb;
    float o[3];
    #pragma unroll
    for (int chn = 0; chn < 3; ++chn) {
        const float* vc = vb + (long long)chn * G3;
        float2 p11 = *reinterpret_cast<const float2*>(vc + o11);
        float2 p12 = *reinterpret_cast<const float2*>(vc + o12);
        float2 p21 = *reinterpret_cast<const float2*>(vc + o21);
        float2 p22 = *reinterpret_cast<const float2*>(vc + o22);
        float a11 = lo ? p11.x : p11.y;
        float a12 = lo ? p12.x : p12.y;
        float a21 = lo ? p21.x : p21.y;
        float a22 = lo ? p22.x : p22.y;
        o[chn] = w11 * (gw * a11 + dw * p11.y)
               + w12 * (gw * a12 + dw * p12.y)
               + w21 * (gw * a21 + dw * p21.y)
               + w22 * (gw * a22 + dw * p22.y);
    }
    float* op = out + pi * 3;
    op[0] = o[0]; op[1] = o[1]; op[2] = o[2];
}

extern "C" void kernel_launch(void* const* d_in, const int* in_sizes, int n_in,
                              void* d_out, int out_size, void* d_ws, size_t ws_size,
                              hipStream_t stream) {
    const float* vel = (const float*)d_in[0];
    const float* pts = (const float*)d_in[1];
    const float* bb  = (const float*)d_in[2];
    float* out = (float*)d_out;

    int B = (int)(in_sizes[0] / (3 * G3));       // 16
    int N = in_sizes[1] / (3 * B);               // 200000
    int total = B * N;                           // 3.2M
    int nbins = B * NBU * NBV;                   // 16384
    int nwin  = (N + WINPTS - 1) / WINPTS;       // 25

    auto align256 = [](size_t x) { return (x + 255) & ~(size_t)255; };
    size_t off_cnt  = 0;
    size_t sz_cnt   = (size_t)nbins * 4;
    size_t off_base = align256(off_cnt + sz_cnt);
    size_t sz_base  = (size_t)(nbins + 1) * 4;
    size_t off_cur  = align256(off_base + sz_base);
    size_t sz_cur   = (size_t)nbins * 4;
    size_t off_pay  = align256(off_cur + sz_cur);
    size_t sz_pay   = (size_t)total * 16;        // 51 MB
    size_t need     = off_pay + sz_pay;

    if (ws_size >= need && B <= 64 && (nbins % 1024) == 0) {
        int*    cnt     = (int*)((char*)d_ws + off_cnt);
        int*    base    = (int*)((char*)d_ws + off_base);
        int*    cursor  = (int*)((char*)d_ws + off_cur);
        float4* payload = (float4*)((char*)d_ws + off_pay);

        hipMemsetAsync(cnt, 0, sz_cnt, stream);

        count_kernel<<<B * nwin, 256, 0, stream>>>(pts, bb, cnt, N, nwin);
        scan_kernel<<<1, 1024, 0, stream>>>(cnt, base, cursor, nbins);
        scatter_kernel<<<B * nwin, 256, 0, stream>>>(pts, bb, cursor, payload, N, nwin);
        trilerp_lds_kernel<<<nbins, 256, 0, stream>>>(vel, base, payload, out);
    } else {
        int nchunk = (N + 255) / 256;
        long long blocks = (long long)B * nchunk * NSLAB;
        trilerp_pair_kernel<<<(int)blocks, 256, 0, stream>>>(vel, pts, bb, out, N, nchunk);
    }
}

// Round 10
// 240.500 us; speedup vs baseline: 3.2019x; 1.0835x over previous
//
#include <hip/hip_runtime.h>

// Trilinear grid interpolation — uv-bin + fused f32 LDS-staged gather.
//   velocity: [B, 3, G, G, G] f32, points: [B, N, 3] f32, bb: [3,2] f32
//   out: [B, N, 3] f32
//
// R1-R8 evidence: gathers must be served from LDS (global gathers are
// L1-miss bound); staging straight from f32 velocity (no materialized
// repack) is cheapest; binning passes must not duplicate work.
// R9: count persists per-window histograms (plain stores) -> scanA
// (per-batch window prefix, 16 blocks) -> scanB (bin-total scan, 1 block)
// -> single-pass scatter (LDS cursor = base+wprefix, rank via LDS atomic).
// Bin linear order = binLocal*B + b (keeps scanA coalesced).

constexpr int G = 128;
constexpr long long G3 = (long long)G * G * G;   // 1<<21
constexpr int NSLAB = 8;            // == #XCDs
constexpr int NBU = 32, NBV = 32;   // 4x4-cell uv bins; 1024 bins/batch
constexpr int NBIN = NBU * NBV;     // 1024
constexpr int WINPTS = 8192;        // points per count/scatter window block
constexpr int RS = 132;             // LDS row stride (floats): 16B-aligned rows

__device__ inline int bin_of(float px, float py, const float* bb, float Gm1) {
    float u = (px - bb[0]) / (bb[1] - bb[0]) * Gm1;
    float v = (py - bb[2]) / (bb[3] - bb[2]) * Gm1;
    int iu1 = (int)fminf(fmaxf(floorf(u), 0.f), Gm1);
    int iv1 = (int)fminf(fmaxf(floorf(v), 0.f), Gm1);
    return ((iu1 >> 2) << 5) | (iv1 >> 2);     // bin within batch, 0..1023
}

// ---- pass 1a: per-window histograms, persisted (exclusive rows, no atomics on HBM path)
__global__ __launch_bounds__(256) void count_kernel(
    const float* __restrict__ pts, const float* __restrict__ bb,
    int* __restrict__ h,            // [B*nwin][NBIN]
    int N, int nwin)
{
    __shared__ int hh[NBIN];
    int b = blockIdx.x / nwin;
    int w = blockIdx.x % nwin;
    for (int i = threadIdx.x; i < NBIN; i += 256) hh[i] = 0;
    __syncthreads();

    const float Gm1 = (float)(G - 1);
    long long pbase = (long long)b * N;
    int n0 = w * WINPTS;
    for (int it = 0; it < WINPTS / 256; ++it) {
        int n = n0 + it * 256 + threadIdx.x;
        if (n < N) {
            const float* p = pts + (pbase + n) * 3;
            atomicAdd(&hh[bin_of(p[0], p[1], bb, Gm1)], 1);
        }
    }
    __syncthreads();
    int* row = h + ((long long)(b * nwin + w) << 10);
    for (int i = threadIdx.x; i < NBIN; i += 256) row[i] = hh[i];
}

// ---- pass 1b: per-batch exclusive prefix over windows (in place); bin totals out
__global__ __launch_bounds__(1024) void scanA_kernel(
    int* __restrict__ h,            // [B*nwin][NBIN] -> becomes wprefix
    int* __restrict__ tot,          // [NBIN*B], lin = binLocal*B + b
    int nwin, int B)
{
    int b = blockIdx.x;
    int t = threadIdx.x;            // binLocal
    int run = 0;
    for (int w = 0; w < nwin; ++w) {
        long long idx = ((long long)(b * nwin + w) << 10) | t;
        int v = h[idx];
        h[idx] = run;
        run += v;
    }
    tot[t * B + b] = run;
}

// ---- pass 1c: exclusive scan over nbins totals (one block) ----
__global__ __launch_bounds__(1024) void scanB_kernel(
    const int* __restrict__ tot, int* __restrict__ base, int nbins)
{
    __shared__ int sh[1024];
    int t = threadIdx.x;
    int per = nbins / 1024;
    int local[64];
    int s = 0;
    for (int j = 0; j < per; ++j) { local[j] = tot[t * per + j]; s += local[j]; }
    sh[t] = s;
    __syncthreads();
    for (int off = 1; off < 1024; off <<= 1) {
        int v = (t >= off) ? sh[t - off] : 0;
        __syncthreads();
        sh[t] += v;
        __syncthreads();
    }
    int run = sh[t] - s;
    for (int j = 0; j < per; ++j) {
        base[t * per + j] = run;
        run += local[j];
    }
    if (t == 1023) base[nbins] = sh[1023];
}

// ---- pass 1d: single-pass scatter (cursor row preloaded, LDS ranks) ----
__global__ __launch_bounds__(256) void scatter_kernel(
    const float* __restrict__ pts, const float* __restrict__ bb,
    const int* __restrict__ h,      // wprefix rows
    const int* __restrict__ base,   // [nbins+1]
    float4* __restrict__ payload,
    int N, int nwin, int B)
{
    __shared__ int cursor[NBIN];
    int b = blockIdx.x / nwin;
    int w = blockIdx.x % nwin;

    const int* row = h + ((long long)(b * nwin + w) << 10);
    for (int i = threadIdx.x; i < NBIN; i += 256)
        cursor[i] = base[i * B + b] + row[i];
    __syncthreads();

    const float Gm1 = (float)(G - 1);
    float bx0 = bb[0], bx1 = bb[1];
    float by0 = bb[2], by1 = bb[3];
    float bz0 = bb[4], bz1 = bb[5];
    long long pbase = (long long)b * N;
    int n0 = w * WINPTS;
    for (int it = 0; it < WINPTS / 256; ++it) {
        int n = n0 + it * 256 + threadIdx.x;
        if (n < N) {
            const float* p = pts + (pbase + n) * 3;
            float px = p[0], py = p[1], pz = p[2];
            float u = (px - bx0) / (bx1 - bx0) * Gm1;
            float v = (py - by0) / (by1 - by0) * Gm1;
            float wz = (pz - bz0) / (bz1 - bz0) * Gm1;
            int iu1 = (int)fminf(fmaxf(floorf(u), 0.f), Gm1);
            int iv1 = (int)fminf(fmaxf(floorf(v), 0.f), Gm1);
            int bin = ((iu1 >> 2) << 5) | (iv1 >> 2);
            int pos = atomicAdd(&cursor[bin], 1);
            payload[pos] = make_float4(u, v, wz, __int_as_float((int)(pbase + n)));
        }
    }
}

// ---- pass 2: binned gather, f32 LDS staging ----
__global__ __launch_bounds__(256) void trilerp_lds_kernel(
    const float* __restrict__ vel,       // [B,3,G,G,G]
    const int* __restrict__ base,        // [nbins+1], lin = binLocal*B + b
    const float4* __restrict__ payload,  // [B*N] {u,v,w,idx}
    float* __restrict__ out,             // [B,N,3]
    int B)
{
    // blockIdx.x = slab + 8*(b*128 + j*32 + iv4);  iu4 = slab*4 + j
    __shared__ float s_vel[3 * 25 * RS];   // 39.6 KB

    int x = blockIdx.x;
    int slab = x & (NSLAB - 1);
    int rest = x >> 3;
    int b    = rest >> 7;
    int r2   = rest & 127;
    int iu4  = (slab << 2) | (r2 >> 5);
    int iv4  = r2 & 31;
    int lin  = ((iu4 << 5) | iv4) * B + b;

    int s = base[lin], e = base[lin + 1];

    int u0 = iu4 << 2, v0 = iv4 << 2;

    // stage 3 channels x 25 rows x 128 cells as float4s, coalesced
    for (int k = 0; k < 10; ++k) {
        int idx = (int)threadIdx.x + k * 256;
        if (idx < 2400) {
            int f4 = idx & 31;
            int ru = idx >> 5;
            int ch = ru / 25;
            int r  = ru - ch * 25;
            int gu = min(u0 + r / 5, G - 1);
            int gv = min(v0 + (r - (r / 5) * 5), G - 1);
            long long src = (((long long)b * 3 + ch) << 21) + ((long long)gu << 14) + (gv << 7) + (f4 << 2);
            float4 val = *reinterpret_cast<const float4*>(vel + src);
            *reinterpret_cast<float4*>(&s_vel[(ch * 25 + r) * RS + (f4 << 2)]) = val;
        }
    }
    __syncthreads();

    if (s == e) return;
    const float Gm1 = (float)(G - 1);

    for (int i = s + (int)threadIdx.x; i < e; i += 256) {
        float4 pl = payload[i];
        float u = pl.x, v = pl.y, w = pl.z;
        int t = __float_as_int(pl.w);

        float fu = fminf(fmaxf(floorf(u), 0.f), Gm1);
        float fv = fminf(fmaxf(floorf(v), 0.f), Gm1);
        float fw = fminf(fmaxf(floorf(w), 0.f), Gm1);

        float du = u - fu, dv = v - fv, dw = w - fw;   // frac
        float gu = fu + 1.0f - u;                      // gfrac
        float gv = fv + 1.0f - v;
        float gw = fw + 1.0f - w;

        int iu1 = (int)fu, iv1 = (int)fv, iw1 = (int)fw;
        int iu2 = min(iu1 + 1, G - 1);
        int iv2 = min(iv1 + 1, G - 1);
        int iwb = min(iw1, G - 2);
        bool lo = (iw1 <= G - 2);

        float w11 = gu * gv, w12 = gu * dv, w21 = du * gv, w22 = du * dv;

        int du1 = iu1 - u0, dv1 = iv1 - v0;
        int du2 = iu2 - u0, dv2 = iv2 - v0;

        float o[3];
        #pragma unroll
        for (int ch = 0; ch < 3; ++ch) {
            int rb = ch * 25;
            const float* c11 = &s_vel[(rb + du1 * 5 + dv1) * RS + iwb];
            const float* c12 = &s_vel[(rb + du1 * 5 + dv2) * RS + iwb];
            const float* c21 = &s_vel[(rb + du2 * 5 + dv1) * RS + iwb];
            const float* c22 = &s_vel[(rb + du2 * 5 + dv2) * RS + iwb];
            float2 p11 = *reinterpret_cast<const float2*>(c11);
            float2 p12 = *reinterpret_cast<const float2*>(c12);
            float2 p21 = *reinterpret_cast<const float2*>(c21);
            float2 p22 = *reinterpret_cast<const float2*>(c22);
            float a11 = lo ? p11.x : p11.y;
            float a12 = lo ? p12.x : p12.y;
            float a21 = lo ? p21.x : p21.y;
            float a22 = lo ? p22.x : p22.y;
            o[ch] = w11 * (gw * a11 + dw * p11.y)
                  + w12 * (gw * a12 + dw * p12.y)
                  + w21 * (gw * a21 + dw * p21.y)
                  + w22 * (gw * a22 + dw * p22.y);
        }

        float* op = out + (long long)t * 3;
        op[0] = o[0]; op[1] = o[1]; op[2] = o[2];
    }
}

// ---- fallback (R3): f32 broadcast scan, no workspace ----
__global__ __launch_bounds__(256) void trilerp_pair_kernel(
    const float* __restrict__ vel, const float* __restrict__ pts,
    const float* __restrict__ bb, float* __restrict__ out,
    int N, int nchunk)
{
    int bid  = blockIdx.x;
    int slab = bid & (NSLAB - 1);
    int t    = bid >> 3;
    int c    = t % nchunk;
    int b    = t / nchunk;
    int n = c * 256 + threadIdx.x;
    if (n >= N) return;

    float bx0 = bb[0], bx1 = bb[1];
    float by0 = bb[2], by1 = bb[3];
    float bz0 = bb[4], bz1 = bb[5];
    long long pi = (long long)b * N + n;
    const float* p = pts + pi * 3;
    float px = p[0], py = p[1], pz = p[2];
    const float Gm1 = (float)(G - 1);
    float u = (px - bx0) / (bx1 - bx0) * Gm1;
    float fu = fminf(fmaxf(floorf(u), 0.f), Gm1);
    int iu1 = (int)fu;
    if ((iu1 >> 4) != slab) return;
    float v = (py - by0) / (by1 - by0) * Gm1;
    float w = (pz - bz0) / (bz1 - bz0) * Gm1;
    float fv = fminf(fmaxf(floorf(v), 0.f), Gm1);
    float fw = fminf(fmaxf(floorf(w), 0.f), Gm1);
    float du = u - fu, dv = v - fv, dw = w - fw;
    float gu = fu + 1.0f - u, gv = fv + 1.0f - v, gw = fw + 1.0f - w;
    int iv1 = (int)fv, iw1 = (int)fw;
    int iu2 = min(iu1 + 1, G - 1);
    int iv2 = min(iv1 + 1, G - 1);
    int iwb = min(iw1, G - 2);
    bool lo = (iw1 <= G - 2);
    float w11 = gu * gv, w12 = gu * dv, w21 = du * gv, w22 = du * dv;
    const float* vb = vel + (long long)b * 3 * G3;
    long long o11 = (long long)((iu1 << 7) + iv1) * G + iwb;
    long long o12 = (long long)((iu1 << 7) + iv2) * G + iwb;
    long long o21 = (long long)((iu2 << 7) + iv1) * G + iwb;
    long long o22 = (long long)((iu2 << 7) + iv2) * G + iwb;
    float o[3];
    #pragma unroll
    for (int chn = 0; chn < 3; ++chn) {
        const float* vc = vb + (long long)chn * G3;
        float2 p11 = *reinterpret_cast<const float2*>(vc + o11);
        float2 p12 = *reinterpret_cast<const float2*>(vc + o12);
        float2 p21 = *reinterpret_cast<const float2*>(vc + o21);
        float2 p22 = *reinterpret_cast<const float2*>(vc + o22);
        float a11 = lo ? p11.x : p11.y;
        float a12 = lo ? p12.x : p12.y;
        float a21 = lo ? p21.x : p21.y;
        float a22 = lo ? p22.x : p22.y;
        o[chn] = w11 * (gw * a11 + dw * p11.y)
               + w12 * (gw * a12 + dw * p12.y)
               + w21 * (gw * a21 + dw * p21.y)
               + w22 * (gw * a22 + dw * p22.y);
    }
    float* op = out + pi * 3;
    op[0] = o[0]; op[1] = o[1]; op[2] = o[2];
}

extern "C" void kernel_launch(void* const* d_in, const int* in_sizes, int n_in,
                              void* d_out, int out_size, void* d_ws, size_t ws_size,
                              hipStream_t stream) {
    const float* vel = (const float*)d_in[0];
    const float* pts = (const float*)d_in[1];
    const float* bb  = (const float*)d_in[2];
    float* out = (float*)d_out;

    int B = (int)(in_sizes[0] / (3 * G3));       // 16
    int N = in_sizes[1] / (3 * B);               // 200000
    int total = B * N;                           // 3.2M
    int nbins = B * NBIN;                        // 16384
    int nwin  = (N + WINPTS - 1) / WINPTS;       // 25

    auto align256 = [](size_t x) { return (x + 255) & ~(size_t)255; };
    size_t off_h    = 0;
    size_t sz_h     = (size_t)B * nwin * NBIN * 4;   // 1.64 MB
    size_t off_tot  = align256(off_h + sz_h);
    size_t sz_tot   = (size_t)nbins * 4;
    size_t off_base = align256(off_tot + sz_tot);
    size_t sz_base  = (size_t)(nbins + 1) * 4;
    size_t off_pay  = align256(off_base + sz_base);
    size_t sz_pay   = (size_t)total * 16;            // 51 MB
    size_t need     = off_pay + sz_pay;

    if (ws_size >= need && B <= 64 && (nbins % 1024) == 0) {
        int*    h       = (int*)((char*)d_ws + off_h);
        int*    tot     = (int*)((char*)d_ws + off_tot);
        int*    base    = (int*)((char*)d_ws + off_base);
        float4* payload = (float4*)((char*)d_ws + off_pay);

        count_kernel<<<B * nwin, 256, 0, stream>>>(pts, bb, h, N, nwin);
        scanA_kernel<<<B, 1024, 0, stream>>>(h, tot, nwin, B);
        scanB_kernel<<<1, 1024, 0, stream>>>(tot, base, nbins);
        scatter_kernel<<<B * nwin, 256, 0, stream>>>(pts, bb, h, base, payload, N, nwin, B);
        trilerp_lds_kernel<<<nbins, 256, 0, stream>>>(vel, base, payload, out, B);
    } else {
        int nchunk = (N + 255) / 256;
        long long blocks = (long long)B * nchunk * NSLAB;
        trilerp_pair_kernel<<<(int)blocks, 256, 0, stream>>>(vel, pts, bb, out, N, nchunk);
    }
}

// Round 11
// 232.326 us; speedup vs baseline: 3.3145x; 1.0352x over previous
//
#include <hip/hip_runtime.h>

// Trilinear grid interpolation — single-pass windowed binning + LDS-staged gather.
//   velocity: [B, 3, G, G, G] f32, points: [B, N, 3] f32, bb: [3,2] f32
//   out: [B, N, 3] f32
//
// R1-R9 evidence: gathers must come from LDS (global gathers L1-miss bound);
// stage straight from f32 velocity; binning must touch points once and use
// enough blocks (old count+scan+scatter = 4 launches, 2 HBM point passes,
// 1.5 blocks/CU). R10: ONE binning kernel with window-segmented payload:
// LDS histogram -> in-block 1024-bin scan -> per-window bin offsets Pt
// (bin-major for gather) -> L2-hot re-read, rank via LDS cursor, write into
// the block's PRIVATE contiguous payload segment. Gather rebuilds the
// per-bin window prefix in LDS (binary search per point).

constexpr int G = 128;
constexpr long long G3 = (long long)G * G * G;   // 1<<21
constexpr int NSLAB = 8;            // == #XCDs
constexpr int NBU = 32, NBV = 32;   // 4x4-cell uv bins
constexpr int NBIN = NBU * NBV;     // 1024
constexpr int WINPTS = 4096;        // points per window block
constexpr int MAXWIN = 64;          // gather LDS arrays cap (N <= 64*4096)

// ---------------- pass 1: windowed binning (hist + scan + scatter) ----------
__global__ __launch_bounds__(256) void bin_kernel(
    const float* __restrict__ pts,   // [B,N,3]
    const float* __restrict__ bb,    // [3,2]
    int* __restrict__ Pt,            // [B*NBIN][nwin] window-local bin offsets
    float4* __restrict__ payload,    // [B*nwin][WINPTS]
    int N, int nwin)
{
    __shared__ int hist[NBIN];
    __shared__ int psum[256];

    int b = blockIdx.x / nwin;
    int w = blockIdx.x % nwin;
    for (int i = threadIdx.x; i < NBIN; i += 256) hist[i] = 0;
    __syncthreads();

    const float Gm1 = (float)(G - 1);
    float bx0 = bb[0], bx1 = bb[1];
    float by0 = bb[2], by1 = bb[3];
    float bz0 = bb[4], bz1 = bb[5];
    long long pbase = (long long)b * N;
    int n0 = w * WINPTS;

    // phase 1: histogram (reads x,y only)
    for (int it = 0; it < WINPTS / 256; ++it) {
        int n = n0 + it * 256 + threadIdx.x;
        if (n < N) {
            const float* p = pts + (pbase + n) * 3;
            float u = (p[0] - bx0) / (bx1 - bx0) * Gm1;
            float v = (p[1] - by0) / (by1 - by0) * Gm1;
            int iu = (int)fminf(fmaxf(floorf(u), 0.f), Gm1);
            int iv = (int)fminf(fmaxf(floorf(v), 0.f), Gm1);
            atomicAdd(&hist[((iu >> 2) << 5) | (iv >> 2)], 1);
        }
    }
    __syncthreads();

    // in-block exclusive scan of 1024 bins: thread t owns bins 4t..4t+3
    int t = threadIdx.x;
    int l0 = hist[4 * t], l1 = hist[4 * t + 1], l2 = hist[4 * t + 2], l3 = hist[4 * t + 3];
    int s = l0 + l1 + l2 + l3;
    psum[t] = s;
    __syncthreads();
    for (int off = 1; off < 256; off <<= 1) {
        int v = (t >= off) ? psum[t - off] : 0;
        __syncthreads();
        psum[t] += v;
        __syncthreads();
    }
    int run = psum[t] - s;   // exclusive prefix of this thread's 4 bins

    // write Pt (bin-major: [(b*NBIN+bin)*nwin + w]) and convert hist -> cursor
    long long prow = ((long long)b * NBIN + 4 * t) * nwin + w;
    Pt[prow]            = run; hist[4 * t]     = run; run += l0;
    Pt[prow + nwin]     = run; hist[4 * t + 1] = run; run += l1;
    Pt[prow + 2 * nwin] = run; hist[4 * t + 2] = run; run += l2;
    Pt[prow + 3 * nwin] = run; hist[4 * t + 3] = run; run += l3;
    __syncthreads();

    // phase 2: re-read (L1/L2-hot), rank, write into private segment
    float4* seg = payload + (long long)(b * nwin + w) * WINPTS;
    for (int it = 0; it < WINPTS / 256; ++it) {
        int n = n0 + it * 256 + threadIdx.x;
        if (n < N) {
            const float* p = pts + (pbase + n) * 3;
            float u  = (p[0] - bx0) / (bx1 - bx0) * Gm1;
            float v  = (p[1] - by0) / (by1 - by0) * Gm1;
            float wz = (p[2] - bz0) / (bz1 - bz0) * Gm1;
            int iu = (int)fminf(fmaxf(floorf(u), 0.f), Gm1);
            int iv = (int)fminf(fmaxf(floorf(v), 0.f), Gm1);
            int bin = ((iu >> 2) << 5) | (iv >> 2);
            int pos = atomicAdd(&hist[bin], 1);
            seg[pos] = make_float4(u, v, wz, __int_as_float((int)(pbase + n)));
        }
    }
}

// ---------------- pass 2: binned gather, f32 LDS staging ----------------
__global__ __launch_bounds__(256) void trilerp_lds_kernel(
    const float* __restrict__ vel,       // [B,3,G,G,G]
    const int* __restrict__ Pt,          // [B*NBIN][nwin]
    const float4* __restrict__ payload,  // [B*nwin][WINPTS]
    float* __restrict__ out,             // [B,N,3]
    int N, int nwin)
{
    // blockIdx.x = slab + 8*(b*128 + j*32 + iv4);  iu4 = slab*4 + j
    __shared__ float s_vel[3 * 25 * 128];   // 38.4 KB -> 4 blocks/CU
    __shared__ int loc[MAXWIN];
    __shared__ int sc[MAXWIN];              // counts -> inclusive prefix

    int x = blockIdx.x;
    int slab = x & (NSLAB - 1);
    int rest = x >> 3;
    int b    = rest >> 7;
    int r2   = rest & 127;
    int iu4  = (slab << 2) | (r2 >> 5);
    int iv4  = r2 & 31;
    int binLocal = (iu4 << 5) | iv4;
    long long lin = (long long)b * NBIN + binLocal;

    int tid = threadIdx.x;
    if (tid < nwin) {
        int l  = Pt[lin * nwin + tid];
        int nl = (binLocal < NBIN - 1) ? Pt[(lin + 1) * nwin + tid]
                                       : min(WINPTS, N - tid * WINPTS);
        loc[tid] = l;
        sc[tid]  = nl - l;                  // count of this bin in window tid
    } else if (tid < MAXWIN) {
        loc[tid] = 0; sc[tid] = 0;
    }

    // stage 3 channels x 25 rows x 128 cells as float4s, coalesced
    int u0 = iu4 << 2, v0 = iv4 << 2;
    for (int k = 0; k < 10; ++k) {
        int idx = tid + k * 256;
        if (idx < 2400) {
            int f4 = idx & 31;
            int ru = idx >> 5;
            int ch = ru / 25;
            int r  = ru - ch * 25;
            int gu = min(u0 + r / 5, G - 1);
            int gv = min(v0 + (r - (r / 5) * 5), G - 1);
            long long src = (((long long)b * 3 + ch) << 21) + ((long long)gu << 14) + (gv << 7) + (f4 << 2);
            float4 val = *reinterpret_cast<const float4*>(vel + src);
            *reinterpret_cast<float4*>(&s_vel[(ch * 25 + r) * 128 + (f4 << 2)]) = val;
        }
    }
    __syncthreads();

    // inclusive prefix over window counts (all threads hit barriers)
    for (int off = 1; off < MAXWIN; off <<= 1) {
        int v = 0;
        if (tid < MAXWIN && tid >= off) v = sc[tid - off];
        __syncthreads();
        if (tid < MAXWIN) sc[tid] += v;
        __syncthreads();
    }
    int total = sc[nwin - 1];
    const float Gm1 = (float)(G - 1);

    for (int i = tid; i < total; i += 256) {
        // smallest w with sc[w] > i
        int lo2 = 0, hi2 = nwin - 1;
        while (lo2 < hi2) { int mid = (lo2 + hi2) >> 1; if (sc[mid] > i) hi2 = mid; else lo2 = mid + 1; }
        int w = lo2;
        int excl = (w == 0) ? 0 : sc[w - 1];
        long long pidx = (long long)(b * nwin + w) * WINPTS + loc[w] + (i - excl);
        float4 pl = payload[pidx];
        float u = pl.x, v = pl.y, wq = pl.z;
        int t = __float_as_int(pl.w);

        float fu = fminf(fmaxf(floorf(u), 0.f), Gm1);
        float fv = fminf(fmaxf(floorf(v), 0.f), Gm1);
        float fw = fminf(fmaxf(floorf(wq), 0.f), Gm1);

        float du = u - fu, dv = v - fv, dw = wq - fw;  // frac
        float gu = fu + 1.0f - u;                      // gfrac
        float gv = fv + 1.0f - v;
        float gw = fw + 1.0f - wq;

        int iu1 = (int)fu, iv1 = (int)fv, iw1 = (int)fw;
        int iu2 = min(iu1 + 1, G - 1);
        int iv2 = min(iv1 + 1, G - 1);
        int iwb = min(iw1, G - 2);
        bool lo = (iw1 <= G - 2);

        float w11 = gu * gv, w12 = gu * dv, w21 = du * gv, w22 = du * dv;

        int du1 = iu1 - u0, dv1 = iv1 - v0;
        int du2 = iu2 - u0, dv2 = iv2 - v0;

        float o[3];
        #pragma unroll
        for (int ch = 0; ch < 3; ++ch) {
            int rb = ch * 25;
            const float* c11 = &s_vel[((rb + du1 * 5 + dv1) << 7) + iwb];
            const float* c12 = &s_vel[((rb + du1 * 5 + dv2) << 7) + iwb];
            const float* c21 = &s_vel[((rb + du2 * 5 + dv1) << 7) + iwb];
            const float* c22 = &s_vel[((rb + du2 * 5 + dv2) << 7) + iwb];
            float2 p11 = *reinterpret_cast<const float2*>(c11);
            float2 p12 = *reinterpret_cast<const float2*>(c12);
            float2 p21 = *reinterpret_cast<const float2*>(c21);
            float2 p22 = *reinterpret_cast<const float2*>(c22);
            float a11 = lo ? p11.x : p11.y;
            float a12 = lo ? p12.x : p12.y;
            float a21 = lo ? p21.x : p21.y;
            float a22 = lo ? p22.x : p22.y;
            o[ch] = w11 * (gw * a11 + dw * p11.y)
                  + w12 * (gw * a12 + dw * p12.y)
                  + w21 * (gw * a21 + dw * p21.y)
                  + w22 * (gw * a22 + dw * p22.y);
        }

        float* op = out + (long long)t * 3;
        op[0] = o[0]; op[1] = o[1]; op[2] = o[2];
    }
}

// ---- fallback (R3): f32 broadcast scan, no workspace ----
__global__ __launch_bounds__(256) void trilerp_pair_kernel(
    const float* __restrict__ vel, const float* __restrict__ pts,
    const float* __restrict__ bb, float* __restrict__ out,
    int N, int nchunk)
{
    int bid  = blockIdx.x;
    int slab = bid & (NSLAB - 1);
    int t    = bid >> 3;
    int c    = t % nchunk;
    int b    = t / nchunk;
    int n = c * 256 + threadIdx.x;
    if (n >= N) return;

    float bx0 = bb[0], bx1 = bb[1];
    float by0 = bb[2], by1 = bb[3];
    float bz0 = bb[4], bz1 = bb[5];
    long long pi = (long long)b * N + n;
    const float* p = pts + pi * 3;
    float px = p[0], py = p[1], pz = p[2];
    const float Gm1 = (float)(G - 1);
    float u = (px - bx0) / (bx1 - bx0) * Gm1;
    float fu = fminf(fmaxf(floorf(u), 0.f), Gm1);
    int iu1 = (int)fu;
    if ((iu1 >> 4) != slab) return;
    float v = (py - by0) / (by1 - by0) * Gm1;
    float w = (pz - bz0) / (bz1 - bz0) * Gm1;
    float fv = fminf(fmaxf(floorf(v), 0.f), Gm1);
    float fw = fminf(fmaxf(floorf(w), 0.f), Gm1);
    float du = u - fu, dv = v - fv, dw = w - fw;
    float gu = fu + 1.0f - u, gv = fv + 1.0f - v, gw = fw + 1.0f - w;
    int iv1 = (int)fv, iw1 = (int)fw;
    int iu2 = min(iu1 + 1, G - 1);
    int iv2 = min(iv1 + 1, G - 1);
    int iwb = min(iw1, G - 2);
    bool lo = (iw1 <= G - 2);
    float w11 = gu * gv, w12 = gu * dv, w21 = du * gv, w22 = du * dv;
    const float* vb = vel + (long long)b * 3 * G3;
    long long o11 = (long long)((iu1 << 7) + iv1) * G + iwb;
    long long o12 = (long long)((iu1 << 7) + iv2) * G + iwb;
    long long o21 = (long long)((iu2 << 7) + iv1) * G + iwb;
    long long o22 = (long long)((iu2 << 7) + iv2) * G + iwb;
    float o[3];
    #pragma unroll
    for (int chn = 0; chn < 3; ++chn) {
        const float* vc = vb + (long long)chn * G3;
        float2 p11 = *reinterpret_cast<const float2*>(vc + o11);
        float2 p12 = *reinterpret_cast<const float2*>(vc + o12);
        float2 p21 = *reinterpret_cast<const float2*>(vc + o21);
        float2 p22 = *reinterpret_cast<const float2*>(vc + o22);
        float a11 = lo ? p11.x : p11.y;
        float a12 = lo ? p12.x : p12.y;
        float a21 = lo ? p21.x : p21.y;
        float a22 = lo ? p22.x : p22.y;
        o[chn] = w11 * (gw * a11 + dw * p11.y)
               + w12 * (gw * a12 + dw * p12.y)
               + w21 * (gw * a21 + dw * p21.y)
               + w22 * (gw * a22 + dw * p22.y);
    }
    float* op = out + pi * 3;
    op[0] = o[0]; op[1] = o[1]; op[2] = o[2];
}

extern "C" void kernel_launch(void* const* d_in, const int* in_sizes, int n_in,
                              void* d_out, int out_size, void* d_ws, size_t ws_size,
                              hipStream_t stream) {
    const float* vel = (const float*)d_in[0];
    const float* pts = (const float*)d_in[1];
    const float* bb  = (const float*)d_in[2];
    float* out = (float*)d_out;

    int B = (int)(in_sizes[0] / (3 * G3));       // 16
    int N = in_sizes[1] / (3 * B);               // 200000
    int nwin = (N + WINPTS - 1) / WINPTS;        // 49

    auto align256 = [](size_t x) { return (x + 255) & ~(size_t)255; };
    size_t off_pt  = 0;
    size_t sz_pt   = (size_t)B * NBIN * nwin * 4;            // 3.2 MB
    size_t off_pay = align256(off_pt + sz_pt);
    size_t sz_pay  = (size_t)B * nwin * WINPTS * 16;         // 51.4 MB
    size_t need    = off_pay + sz_pay;

    if (ws_size >= need && nwin <= MAXWIN) {
        int*    Pt      = (int*)((char*)d_ws + off_pt);
        float4* payload = (float4*)((char*)d_ws + off_pay);

        bin_kernel<<<B * nwin, 256, 0, stream>>>(pts, bb, Pt, payload, N, nwin);
        trilerp_lds_kernel<<<B * NBIN, 256, 0, stream>>>(vel, Pt, payload, out, N, nwin);
    } else {
        int nchunk = (N + 255) / 256;
        long long blocks = (long long)B * nchunk * NSLAB;
        trilerp_pair_kernel<<<(int)blocks, 256, 0, stream>>>(vel, pts, bb, out, N, nchunk);
    }
}

// Round 12
// 196.389 us; speedup vs baseline: 3.9211x; 1.1830x over previous
//
#include <hip/hip_runtime.h>
#include <hip/hip_fp16.h>

// Trilinear grid interpolation — windowed binning + fp16-LDS-staged gather.
//   velocity: [B, 3, G, G, G] f32, points: [B, N, 3] f32, bb: [3,2] f32
//   out: [B, N, 3] f32
//
// R10 analysis: gather (~180us) sits ~100us above its HBM floor; cause is
// 4 blocks/CU (38.4KB f32 LDS tile) = 16 waves/CU of latency hiding on a
// stage->barrier->compute loop. R11: stage fp16 planar [3][25][128] (19.2KB,
// convert f32->fp16 during LDS write; global reads stay f32) -> 8 blocks/CU,
// 32 waves. fp16 cell precision validated R5-R7 (absmax unchanged).

constexpr int G = 128;
constexpr long long G3 = (long long)G * G * G;   // 1<<21
constexpr int NSLAB = 8;            // == #XCDs
constexpr int NBU = 32, NBV = 32;   // 4x4-cell uv bins
constexpr int NBIN = NBU * NBV;     // 1024
constexpr int WINPTS = 4096;        // points per window block
constexpr int MAXWIN = 64;          // gather LDS arrays cap (N <= 64*4096)

// ---------------- pass 1: windowed binning (hist + scan + scatter) ----------
__global__ __launch_bounds__(256) void bin_kernel(
    const float* __restrict__ pts,   // [B,N,3]
    const float* __restrict__ bb,    // [3,2]
    int* __restrict__ Pt,            // [B*NBIN][nwin] window-local bin offsets
    float4* __restrict__ payload,    // [B*nwin][WINPTS]
    int N, int nwin)
{
    __shared__ int hist[NBIN];
    __shared__ int psum[256];

    int b = blockIdx.x / nwin;
    int w = blockIdx.x % nwin;
    for (int i = threadIdx.x; i < NBIN; i += 256) hist[i] = 0;
    __syncthreads();

    const float Gm1 = (float)(G - 1);
    float bx0 = bb[0], bx1 = bb[1];
    float by0 = bb[2], by1 = bb[3];
    float bz0 = bb[4], bz1 = bb[5];
    long long pbase = (long long)b * N;
    int n0 = w * WINPTS;

    // phase 1: histogram (reads x,y only)
    for (int it = 0; it < WINPTS / 256; ++it) {
        int n = n0 + it * 256 + threadIdx.x;
        if (n < N) {
            const float* p = pts + (pbase + n) * 3;
            float u = (p[0] - bx0) / (bx1 - bx0) * Gm1;
            float v = (p[1] - by0) / (by1 - by0) * Gm1;
            int iu = (int)fminf(fmaxf(floorf(u), 0.f), Gm1);
            int iv = (int)fminf(fmaxf(floorf(v), 0.f), Gm1);
            atomicAdd(&hist[((iu >> 2) << 5) | (iv >> 2)], 1);
        }
    }
    __syncthreads();

    // in-block exclusive scan of 1024 bins: thread t owns bins 4t..4t+3
    int t = threadIdx.x;
    int l0 = hist[4 * t], l1 = hist[4 * t + 1], l2 = hist[4 * t + 2], l3 = hist[4 * t + 3];
    int s = l0 + l1 + l2 + l3;
    psum[t] = s;
    __syncthreads();
    for (int off = 1; off < 256; off <<= 1) {
        int v = (t >= off) ? psum[t - off] : 0;
        __syncthreads();
        psum[t] += v;
        __syncthreads();
    }
    int run = psum[t] - s;   // exclusive prefix of this thread's 4 bins

    // write Pt (bin-major: [(b*NBIN+bin)*nwin + w]) and convert hist -> cursor
    long long prow = ((long long)b * NBIN + 4 * t) * nwin + w;
    Pt[prow]            = run; hist[4 * t]     = run; run += l0;
    Pt[prow + nwin]     = run; hist[4 * t + 1] = run; run += l1;
    Pt[prow + 2 * nwin] = run; hist[4 * t + 2] = run; run += l2;
    Pt[prow + 3 * nwin] = run; hist[4 * t + 3] = run; run += l3;
    __syncthreads();

    // phase 2: re-read (L1/L2-hot), rank, write into private segment
    float4* seg = payload + (long long)(b * nwin + w) * WINPTS;
    for (int it = 0; it < WINPTS / 256; ++it) {
        int n = n0 + it * 256 + threadIdx.x;
        if (n < N) {
            const float* p = pts + (pbase + n) * 3;
            float u  = (p[0] - bx0) / (bx1 - bx0) * Gm1;
            float v  = (p[1] - by0) / (by1 - by0) * Gm1;
            float wz = (p[2] - bz0) / (bz1 - bz0) * Gm1;
            int iu = (int)fminf(fmaxf(floorf(u), 0.f), Gm1);
            int iv = (int)fminf(fmaxf(floorf(v), 0.f), Gm1);
            int bin = ((iu >> 2) << 5) | (iv >> 2);
            int pos = atomicAdd(&hist[bin], 1);
            seg[pos] = make_float4(u, v, wz, __int_as_float((int)(pbase + n)));
        }
    }
}

// ---------------- pass 2: binned gather, fp16 planar LDS staging ------------
__global__ __launch_bounds__(256) void trilerp_lds_kernel(
    const float* __restrict__ vel,       // [B,3,G,G,G]
    const int* __restrict__ Pt,          // [B*NBIN][nwin]
    const float4* __restrict__ payload,  // [B*nwin][WINPTS]
    float* __restrict__ out,             // [B,N,3]
    int N, int nwin)
{
    // blockIdx.x = slab + 8*(b*128 + j*32 + iv4);  iu4 = slab*4 + j
    __shared__ unsigned short s_h[3 * 25 * 128];  // 19.2 KB -> 8 blocks/CU
    __shared__ int loc[MAXWIN];
    __shared__ int sc[MAXWIN];                    // counts -> inclusive prefix

    int x = blockIdx.x;
    int slab = x & (NSLAB - 1);
    int rest = x >> 3;
    int b    = rest >> 7;
    int r2   = rest & 127;
    int iu4  = (slab << 2) | (r2 >> 5);
    int iv4  = r2 & 31;
    int binLocal = (iu4 << 5) | iv4;
    long long lin = (long long)b * NBIN + binLocal;

    int tid = threadIdx.x;
    if (tid < nwin) {
        int l  = Pt[lin * nwin + tid];
        int nl = (binLocal < NBIN - 1) ? Pt[(lin + 1) * nwin + tid]
                                       : min(WINPTS, N - tid * WINPTS);
        loc[tid] = l;
        sc[tid]  = nl - l;                  // count of this bin in window tid
    } else if (tid < MAXWIN) {
        loc[tid] = 0; sc[tid] = 0;
    }

    // stage 3 channels x 25 rows x 128 cells: f32 global -> fp16 LDS, coalesced
    int u0 = iu4 << 2, v0 = iv4 << 2;
    for (int k = 0; k < 10; ++k) {
        int idx = tid + k * 256;
        if (idx < 2400) {
            int f4 = idx & 31;
            int ru = idx >> 5;
            int ch = ru / 25;
            int r  = ru - ch * 25;
            int gu = min(u0 + r / 5, G - 1);
            int gv = min(v0 + (r - (r / 5) * 5), G - 1);
            long long src = (((long long)b * 3 + ch) << 21) + ((long long)gu << 14) + (gv << 7) + (f4 << 2);
            float4 val = *reinterpret_cast<const float4*>(vel + src);
            unsigned int lo32 = (unsigned int)__half_as_ushort(__float2half(val.x))
                              | ((unsigned int)__half_as_ushort(__float2half(val.y)) << 16);
            unsigned int hi32 = (unsigned int)__half_as_ushort(__float2half(val.z))
                              | ((unsigned int)__half_as_ushort(__float2half(val.w)) << 16);
            *reinterpret_cast<uint2*>(&s_h[((ch * 25 + r) << 7) + (f4 << 2)]) = make_uint2(lo32, hi32);
        }
    }
    __syncthreads();

    // inclusive prefix over window counts (all threads hit barriers)
    for (int off = 1; off < MAXWIN; off <<= 1) {
        int v = 0;
        if (tid < MAXWIN && tid >= off) v = sc[tid - off];
        __syncthreads();
        if (tid < MAXWIN) sc[tid] += v;
        __syncthreads();
    }
    int total = sc[nwin - 1];
    const float Gm1 = (float)(G - 1);

    auto h2f = [](unsigned short us) -> float {
        return __half2float(__ushort_as_half(us));
    };

    for (int i = tid; i < total; i += 256) {
        // smallest w with sc[w] > i
        int lo2 = 0, hi2 = nwin - 1;
        while (lo2 < hi2) { int mid = (lo2 + hi2) >> 1; if (sc[mid] > i) hi2 = mid; else lo2 = mid + 1; }
        int w = lo2;
        int excl = (w == 0) ? 0 : sc[w - 1];
        long long pidx = (long long)(b * nwin + w) * WINPTS + loc[w] + (i - excl);
        float4 pl = payload[pidx];
        float u = pl.x, v = pl.y, wq = pl.z;
        int t = __float_as_int(pl.w);

        float fu = fminf(fmaxf(floorf(u), 0.f), Gm1);
        float fv = fminf(fmaxf(floorf(v), 0.f), Gm1);
        float fw = fminf(fmaxf(floorf(wq), 0.f), Gm1);

        float du = u - fu, dv = v - fv, dw = wq - fw;  // frac
        float gu = fu + 1.0f - u;                      // gfrac
        float gv = fv + 1.0f - v;
        float gw = fw + 1.0f - wq;

        int iu1 = (int)fu, iv1 = (int)fv, iw1 = (int)fw;
        int iu2 = min(iu1 + 1, G - 1);
        int iv2 = min(iv1 + 1, G - 1);
        int iwb = min(iw1, G - 2);
        bool lo = (iw1 <= G - 2);

        float w11 = gu * gv, w12 = gu * dv, w21 = du * gv, w22 = du * dv;

        int du1 = iu1 - u0, dv1 = iv1 - v0;
        int du2 = iu2 - u0, dv2 = iv2 - v0;

        float o[3];
        #pragma unroll
        for (int ch = 0; ch < 3; ++ch) {
            int rb = ch * 25;
            int b11 = (rb + du1 * 5 + dv1) << 7;
            int b12 = (rb + du1 * 5 + dv2) << 7;
            int b21 = (rb + du2 * 5 + dv1) << 7;
            int b22 = (rb + du2 * 5 + dv2) << 7;
            float l11 = h2f(s_h[b11 + iwb]), h11 = h2f(s_h[b11 + iwb + 1]);
            float l12 = h2f(s_h[b12 + iwb]), h12 = h2f(s_h[b12 + iwb + 1]);
            float l21 = h2f(s_h[b21 + iwb]), h21 = h2f(s_h[b21 + iwb + 1]);
            float l22 = h2f(s_h[b22 + iwb]), h22 = h2f(s_h[b22 + iwb + 1]);
            float a11 = lo ? l11 : h11;
            float a12 = lo ? l12 : h12;
            float a21 = lo ? l21 : h21;
            float a22 = lo ? l22 : h22;
            o[ch] = w11 * (gw * a11 + dw * h11)
                  + w12 * (gw * a12 + dw * h12)
                  + w21 * (gw * a21 + dw * h21)
                  + w22 * (gw * a22 + dw * h22);
        }

        float* op = out + (long long)t * 3;
        op[0] = o[0]; op[1] = o[1]; op[2] = o[2];
    }
}

// ---- fallback (R3): f32 broadcast scan, no workspace ----
__global__ __launch_bounds__(256) void trilerp_pair_kernel(
    const float* __restrict__ vel, const float* __restrict__ pts,
    const float* __restrict__ bb, float* __restrict__ out,
    int N, int nchunk)
{
    int bid  = blockIdx.x;
    int slab = bid & (NSLAB - 1);
    int t    = bid >> 3;
    int c    = t % nchunk;
    int b    = t / nchunk;
    int n = c * 256 + threadIdx.x;
    if (n >= N) return;

    float bx0 = bb[0], bx1 = bb[1];
    float by0 = bb[2], by1 = bb[3];
    float bz0 = bb[4], bz1 = bb[5];
    long long pi = (long long)b * N + n;
    const float* p = pts + pi * 3;
    float px = p[0], py = p[1], pz = p[2];
    const float Gm1 = (float)(G - 1);
    float u = (px - bx0) / (bx1 - bx0) * Gm1;
    float fu = fminf(fmaxf(floorf(u), 0.f), Gm1);
    int iu1 = (int)fu;
    if ((iu1 >> 4) != slab) return;
    float v = (py - by0) / (by1 - by0) * Gm1;
    float w = (pz - bz0) / (bz1 - bz0) * Gm1;
    float fv = fminf(fmaxf(floorf(v), 0.f), Gm1);
    float fw = fminf(fmaxf(floorf(w), 0.f), Gm1);
    float du = u - fu, dv = v - fv, dw = w - fw;
    float gu = fu + 1.0f - u, gv = fv + 1.0f - v, gw = fw + 1.0f - w;
    int iv1 = (int)fv, iw1 = (int)fw;
    int iu2 = min(iu1 + 1, G - 1);
    int iv2 = min(iv1 + 1, G - 1);
    int iwb = min(iw1, G - 2);
    bool lo = (iw1 <= G - 2);
    float w11 = gu * gv, w12 = gu * dv, w21 = du * gv, w22 = du * dv;
    const float* vb = vel + (long long)b * 3 * G3;
    long long o11 = (long long)((iu1 << 7) + iv1) * G + iwb;
    long long o12 = (long long)((iu1 << 7) + iv2) * G + iwb;
    long long o21 = (long long)((iu2 << 7) + iv1) * G + iwb;
    long long o22 = (long long)((iu2 << 7) + iv2) * G + iwb;
    float o[3];
    #pragma unroll
    for (int chn = 0; chn < 3; ++chn) {
        const float* vc = vb + (long long)chn * G3;
        float2 p11 = *reinterpret_cast<const float2*>(vc + o11);
        float2 p12 = *reinterpret_cast<const float2*>(vc + o12);
        float2 p21 = *reinterpret_cast<const float2*>(vc + o21);
        float2 p22 = *reinterpret_cast<const float2*>(vc + o22);
        float a11 = lo ? p11.x : p11.y;
        float a12 = lo ? p12.x : p12.y;
        float a21 = lo ? p21.x : p21.y;
        float a22 = lo ? p22.x : p22.y;
        o[chn] = w11 * (gw * a11 + dw * p11.y)
               + w12 * (gw * a12 + dw * p12.y)
               + w21 * (gw * a21 + dw * p21.y)
               + w22 * (gw * a22 + dw * p22.y);
    }
    float* op = out + pi * 3;
    op[0] = o[0]; op[1] = o[1]; op[2] = o[2];
}

extern "C" void kernel_launch(void* const* d_in, const int* in_sizes, int n_in,
                              void* d_out, int out_size, void* d_ws, size_t ws_size,
                              hipStream_t stream) {
    const float* vel = (const float*)d_in[0];
    const float* pts = (const float*)d_in[1];
    const float* bb  = (const float*)d_in[2];
    float* out = (float*)d_out;

    int B = (int)(in_sizes[0] / (3 * G3));       // 16
    int N = in_sizes[1] / (3 * B);               // 200000
    int nwin = (N + WINPTS - 1) / WINPTS;        // 49

    auto align256 = [](size_t x) { return (x + 255) & ~(size_t)255; };
    size_t off_pt  = 0;
    size_t sz_pt   = (size_t)B * NBIN * nwin * 4;            // 3.2 MB
    size_t off_pay = align256(off_pt + sz_pt);
    size_t sz_pay  = (size_t)B * nwin * WINPTS * 16;         // 51.4 MB
    size_t need    = off_pay + sz_pay;

    if (ws_size >= need && nwin <= MAXWIN) {
        int*    Pt      = (int*)((char*)d_ws + off_pt);
        float4* payload = (float4*)((char*)d_ws + off_pay);

        bin_kernel<<<B * nwin, 256, 0, stream>>>(pts, bb, Pt, payload, N, nwin);
        trilerp_lds_kernel<<<B * NBIN, 256, 0, stream>>>(vel, Pt, payload, out, N, nwin);
    } else {
        int nchunk = (N + 255) / 256;
        long long blocks = (long long)B * nchunk * NSLAB;
        trilerp_pair_kernel<<<(int)blocks, 256, 0, stream>>>(vel, pts, bb, out, N, nchunk);
    }
}